// Round 13
// baseline (233.434 us; speedup 1.0000x reference)
//
#include <hip/hip_runtime.h>
#include <math.h>

#define TT 512
#define LOG2E 1.4426950408889634f

__device__ __forceinline__ float fast_rcp(float v)  { return __builtin_amdgcn_rcpf(v); }
__device__ __forceinline__ float fast_exp2(float v) { return __builtin_amdgcn_exp2f(v); }

// 2 batches per wave. Lane l: grp=l>>5 (batch), half=(l>>4)&1, j=l&15 (unit).
// half0 owns gate rows {i(j), g(j)}; half1 owns {f(j), o(j)}. Single crossing
// per layer (p = i*g shipped to half1 via ds_swizzle xor16).
// R12 change vs R11: ALL ds_reads are prefetch-style. h0[t] is read back into
// v32-47 immediately after its ds_write (regs dead: partA consumed old h0 --
// VALU reads operands at issue, later load writeback can't clobber), h1 and x
// likewise right after their writes/uses. Loop-top reads eliminated; next
// iteration's first 8 L0 pk hoisted before the p1 wait. Counted lgkmcnt()
// exploits per-wave in-order DS completion. Accumulation order bit-identical
// to R11 (verified absmax 0.0).
__global__ __launch_bounds__(64, 2)
void lstm2_wave(const float* __restrict__ x,
                const float* __restrict__ W_ih0, const float* __restrict__ W_hh0,
                const float* __restrict__ b_ih0, const float* __restrict__ b_hh0,
                const float* __restrict__ W_ih1, const float* __restrict__ W_hh1,
                const float* __restrict__ b_ih1, const float* __restrict__ b_hh1,
                const float* __restrict__ W_fc,  const float* __restrict__ b_fc,
                float* __restrict__ out)
{
    const int l    = threadIdx.x;
    const int grp  = l >> 5;         // batch within wave
    const int half = (l >> 4) & 1;   // 0: gates i,g ; 1: gates f,o
    const int j    = l & 15;         // hidden unit
    const int bid  = blockIdx.x;

    const int ra0 = half * 16 + j;   // slot0 row (i or f)
    const int ra1 = ra0 + 32;        // slot1 row (g or o)

    // LDS floats: [0,40) grp0 {h0[16], h1[16], pad8} | [40,80) grp1 | [80,144) trash
    //             | [144,1168) x[2][512] | [1168,1172) pad (final x[512] prefetch)
    __shared__ float lds[1172];

    // ---- stage x (2 batches, 1024 floats) coalesced ----
    {
        const float4* xg = (const float4*)(x + (size_t)bid * 1024);
        float4* xl = (float4*)&lds[144];
        xl[l]       = xg[l];
        xl[l + 64]  = xg[l + 64];
        xl[l + 128] = xg[l + 128];
        xl[l + 192] = xg[l + 192];
    }
    __syncthreads();

    const float bb0a = b_ih0[ra0] + b_hh0[ra0];
    const float bb0b = b_ih0[ra1] + b_hh0[ra1];
    const float bb1a = b_ih1[ra0] + b_hh1[ra0];
    const float bb1b = b_ih1[ra1] + b_hh1[ra1];
    const float wxa  = W_ih0[ra0];
    const float wxb  = W_ih0[ra1];
    // slot1 activation consts: half0 -> tanh (g), half1 -> sigmoid (o)
    const float Ca1 = half ? (-LOG2E) : (-2.0f * LOG2E);
    const float Aa1 = half ? 1.0f : 2.0f;
    const float Ba1 = half ? 0.0f : -1.0f;
    const float nl2e = -LOG2E;

    // half1 writes real h; half0 writes trash
    const int widx = half ? (grp * 40 + j) : (80 + grp * 32 + j);

    // ---- peel t = 0 (h,c = 0: gates from bias + x only) ----
    float cs0, cs1 = 0.0f;
    {
        const float x0 = lds[144 + grp * 512];
        const float a_s0 = fmaf(x0, wxa, bb0a);
        const float a_s1 = fmaf(x0, wxb, bb0b);
        const float s0 = fast_rcp(1.0f + fast_exp2(a_s0 * nl2e));                 // i / f
        const float s1 = fmaf(Aa1, fast_rcp(1.0f + fast_exp2(a_s1 * Ca1)), Ba1);  // g / o
        const float p  = s0 * s1;               // half0: i*g
        const float psw = __shfl_xor(p, 16);    // half1 receives i*g
        cs0 = psw;                              // c0 = f*0 + i*g (valid on half1)
        const float e = fast_exp2(fabsf(cs0) * (2.0f * LOG2E));
        float th = fmaf(-2.0f, fast_rcp(e + 1.0f), 1.0f);
        th = copysignf(th, cs0);
        const float h0v = s1 * th;              // half1: o * tanh(c0)
        lds[widx]      = h0v;                   // half0 lands in trash
        lds[widx + 16] = 0.0f;                  // h1 = 0
    }

    // ---- asm loop: t = 1..511. Explicit regs v24-v185. ----
    {
        unsigned base = (unsigned)(size_t)(void*)&lds[0];
        unsigned hb   = base + grp * 160;                 // h read base (bytes)
        unsigned xa   = base + 576 + grp * 2048 + 4;      // &x[grp][1]
        unsigned wb_  = base + widx * 4;                  // write addr
        const float* pwa = W_hh0 + ra0 * 16;              // slot1 row at +2048B
        const float* pwb = W_ih1 + ra0 * 16;
        const float* pwc = W_hh1 + ra0 * 16;

        asm volatile(
            // ---------- prologue: weights, consts, initial h/x, first 8 L0 pk ----------
            "s_waitcnt lgkmcnt(0)\n"
            "global_load_dwordx4 v[80:83],   %[pwa], off\n"
            "global_load_dwordx4 v[84:87],   %[pwa], off offset:16\n"
            "global_load_dwordx4 v[88:91],   %[pwa], off offset:32\n"
            "global_load_dwordx4 v[92:95],   %[pwa], off offset:48\n"
            "global_load_dwordx4 v[96:99],   %[pwa], off offset:2048\n"
            "global_load_dwordx4 v[100:103], %[pwa], off offset:2064\n"
            "global_load_dwordx4 v[104:107], %[pwa], off offset:2080\n"
            "global_load_dwordx4 v[108:111], %[pwa], off offset:2096\n"
            "global_load_dwordx4 v[112:115], %[pwb], off\n"
            "global_load_dwordx4 v[116:119], %[pwb], off offset:16\n"
            "global_load_dwordx4 v[120:123], %[pwb], off offset:32\n"
            "global_load_dwordx4 v[124:127], %[pwb], off offset:48\n"
            "global_load_dwordx4 v[128:131], %[pwb], off offset:2048\n"
            "global_load_dwordx4 v[132:135], %[pwb], off offset:2064\n"
            "global_load_dwordx4 v[136:139], %[pwb], off offset:2080\n"
            "global_load_dwordx4 v[140:143], %[pwb], off offset:2096\n"
            "global_load_dwordx4 v[144:147], %[pwc], off\n"
            "global_load_dwordx4 v[148:151], %[pwc], off offset:16\n"
            "global_load_dwordx4 v[152:155], %[pwc], off offset:32\n"
            "global_load_dwordx4 v[156:159], %[pwc], off offset:48\n"
            "global_load_dwordx4 v[160:163], %[pwc], off offset:2048\n"
            "global_load_dwordx4 v[164:167], %[pwc], off offset:2064\n"
            "global_load_dwordx4 v[168:171], %[pwc], off offset:2080\n"
            "global_load_dwordx4 v[172:175], %[pwc], off offset:2096\n"
            "v_mov_b32 v24, %[wb]\n"
            "v_mov_b32 v25, %[hb]\n"
            "v_mov_b32 v26, %[xa]\n"
            "v_mov_b32 v176, %[c0i]\n"
            "v_mov_b32 v177, %[c1]\n"
            "v_mov_b32 v178, %[bb0a]\n"
            "v_mov_b32 v179, 0\n"
            "v_mov_b32 v180, %[bb0b]\n"
            "v_mov_b32 v181, 0\n"
            "v_mov_b32 v182, %[bb1a]\n"
            "v_mov_b32 v183, 0\n"
            "v_mov_b32 v184, %[bb1b]\n"
            "v_mov_b32 v185, 0\n"
            "s_movk_i32 s22, 511\n"
            "s_mov_b32 s20, 0x7fffffff\n"
            "s_mov_b32 s21, 0x4038aa3b\n"       // 2*log2(e)
            "ds_read_b32  v27, v26\n"                  // x[1]
            "v_add_u32 v26, 4, v26\n"
            "ds_read_b128 v[32:35], v25\n"             // h0[0]
            "ds_read_b128 v[36:39], v25 offset:16\n"
            "ds_read_b128 v[40:43], v25 offset:32\n"
            "ds_read_b128 v[44:47], v25 offset:48\n"
            "ds_read_b128 v[48:51], v25 offset:64\n"   // h1[0]
            "ds_read_b128 v[52:55], v25 offset:80\n"
            "ds_read_b128 v[56:59], v25 offset:96\n"
            "ds_read_b128 v[60:63], v25 offset:112\n"
            "s_waitcnt vmcnt(0) lgkmcnt(0)\n"
            // hoisted: L0 k0..7 for t=1 (bias folded into C of first pk)
            "v_pk_fma_f32 v[64:65], v[80:81],  v[32:33], v[178:179]\n"
            "v_pk_fma_f32 v[66:67], v[96:97],  v[32:33], v[180:181]\n"
            "v_pk_fma_f32 v[64:65], v[82:83],  v[34:35], v[64:65]\n"
            "v_pk_fma_f32 v[66:67], v[98:99],  v[34:35], v[66:67]\n"
            "v_pk_fma_f32 v[64:65], v[84:85],  v[36:37], v[64:65]\n"
            "v_pk_fma_f32 v[66:67], v[100:101], v[36:37], v[66:67]\n"
            "v_pk_fma_f32 v[64:65], v[86:87],  v[38:39], v[64:65]\n"
            "v_pk_fma_f32 v[66:67], v[102:103], v[38:39], v[66:67]\n"
            "Llstm_%=:\n"
            // ---------- A: L0 k8..15 (h0 resident) ----------
            "v_pk_fma_f32 v[64:65], v[88:89],  v[40:41], v[64:65]\n"
            "v_pk_fma_f32 v[66:67], v[104:105], v[40:41], v[66:67]\n"
            "v_pk_fma_f32 v[64:65], v[90:91],  v[42:43], v[64:65]\n"
            "v_pk_fma_f32 v[66:67], v[106:107], v[42:43], v[66:67]\n"
            "v_pk_fma_f32 v[64:65], v[92:93],  v[44:45], v[64:65]\n"
            "v_pk_fma_f32 v[66:67], v[108:109], v[44:45], v[66:67]\n"
            "v_pk_fma_f32 v[64:65], v[94:95],  v[46:47], v[64:65]\n"
            "v_pk_fma_f32 v[66:67], v[110:111], v[46:47], v[66:67]\n"
            // ---------- B: L0 finish + acts ----------
            "v_add_f32 v28, v64, v65\n"
            "v_add_f32 v29, v66, v67\n"
            "v_fmac_f32 v28, v27, %[wxa]\n"
            "v_fmac_f32 v29, v27, %[wxb]\n"
            "v_mul_f32 v72, %[nl2e], v28\n"
            "v_mul_f32 v73, %[Ca1], v29\n"
            "v_exp_f32 v72, v72\n"
            "v_exp_f32 v73, v73\n"
            "v_add_f32 v72, 1.0, v72\n"
            "v_add_f32 v73, 1.0, v73\n"
            "v_rcp_f32 v72, v72\n"
            "v_rcp_f32 v73, v73\n"
            "s_nop 0\n"
            "v_fma_f32 v73, %[Aa1], v73, %[Ba1]\n"
            "v_mul_f32 v28, v72, v73\n"                // p0 = i0*g0 (half0)
            // ---------- C: ship p0 to half1 ----------
            "ds_swizzle_b32 v76, v28 offset:0x401F\n"
            // ---------- D: L1 partA 16 pk (old h0, v32-47) ----------
            "v_pk_fma_f32 v[68:69], v[112:113], v[32:33], v[182:183]\n"
            "v_pk_fma_f32 v[70:71], v[128:129], v[32:33], v[184:185]\n"
            "v_pk_fma_f32 v[68:69], v[114:115], v[34:35], v[68:69]\n"
            "v_pk_fma_f32 v[70:71], v[130:131], v[34:35], v[70:71]\n"
            "v_pk_fma_f32 v[68:69], v[116:117], v[36:37], v[68:69]\n"
            "v_pk_fma_f32 v[70:71], v[132:133], v[36:37], v[70:71]\n"
            "v_pk_fma_f32 v[68:69], v[118:119], v[38:39], v[68:69]\n"
            "v_pk_fma_f32 v[70:71], v[134:135], v[38:39], v[70:71]\n"
            "v_pk_fma_f32 v[68:69], v[120:121], v[40:41], v[68:69]\n"
            "v_pk_fma_f32 v[70:71], v[136:137], v[40:41], v[70:71]\n"
            "v_pk_fma_f32 v[68:69], v[122:123], v[42:43], v[68:69]\n"
            "v_pk_fma_f32 v[70:71], v[138:139], v[42:43], v[70:71]\n"
            "v_pk_fma_f32 v[68:69], v[124:125], v[44:45], v[68:69]\n"
            "v_pk_fma_f32 v[70:71], v[140:141], v[44:45], v[70:71]\n"
            "v_pk_fma_f32 v[68:69], v[126:127], v[46:47], v[68:69]\n"
            "v_pk_fma_f32 v[70:71], v[142:143], v[46:47], v[70:71]\n"
            // h1' (prefetched prev iter) guaranteed: only p0 may stay outstanding
            "s_waitcnt lgkmcnt(1)\n"
            // ---------- E: L1 partB k0..7 (h1 v48-55) ----------
            "v_pk_fma_f32 v[68:69], v[144:145], v[48:49], v[68:69]\n"
            "v_pk_fma_f32 v[70:71], v[160:161], v[48:49], v[70:71]\n"
            "v_pk_fma_f32 v[68:69], v[146:147], v[50:51], v[68:69]\n"
            "v_pk_fma_f32 v[70:71], v[162:163], v[50:51], v[70:71]\n"
            "v_pk_fma_f32 v[68:69], v[148:149], v[52:53], v[68:69]\n"
            "v_pk_fma_f32 v[70:71], v[164:165], v[52:53], v[70:71]\n"
            "v_pk_fma_f32 v[68:69], v[150:151], v[54:55], v[68:69]\n"
            "v_pk_fma_f32 v[70:71], v[166:167], v[54:55], v[70:71]\n"
            // ---------- F/G: c0 / tanh / h0 on half1 ----------
            "s_waitcnt lgkmcnt(0)\n"                   // p0 done
            "v_fma_f32 v176, v72, v176, v76\n"         // c0 = f0*c0 + p0
            "v_mul_f32 v29, s21, |v176|\n"
            "v_exp_f32 v29, v29\n"
            "s_nop 0\n"
            "v_add_f32 v29, 1.0, v29\n"
            "v_rcp_f32 v29, v29\n"
            "s_nop 0\n"
            "v_fma_f32 v29, -2.0, v29, 1.0\n"
            "v_bfi_b32 v29, s20, v29, v176\n"
            "v_mul_f32 v28, v73, v29\n"                // h0n (half1: v73 = o0)
            // ---------- H/I/J: write h0, PREFETCH h0' + x' (v32-47, v27 dead) ----------
            "ds_write_b32 v24, v28\n"
            "ds_read_b128 v[32:35], v25\n"
            "ds_read_b128 v[36:39], v25 offset:16\n"
            "ds_read_b128 v[40:43], v25 offset:32\n"
            "ds_read_b128 v[44:47], v25 offset:48\n"
            "ds_read_b32  v27, v26\n"
            "v_add_u32 v26, 4, v26\n"
            // ---------- K: L1 partB k8..15 (h1 v56-63, untouched) ----------
            "v_pk_fma_f32 v[68:69], v[152:153], v[56:57], v[68:69]\n"
            "v_pk_fma_f32 v[70:71], v[168:169], v[56:57], v[70:71]\n"
            "v_pk_fma_f32 v[68:69], v[154:155], v[58:59], v[68:69]\n"
            "v_pk_fma_f32 v[70:71], v[170:171], v[58:59], v[70:71]\n"
            "v_pk_fma_f32 v[68:69], v[156:157], v[60:61], v[68:69]\n"
            "v_pk_fma_f32 v[70:71], v[172:173], v[60:61], v[70:71]\n"
            "v_pk_fma_f32 v[68:69], v[158:159], v[62:63], v[68:69]\n"
            "v_pk_fma_f32 v[70:71], v[174:175], v[62:63], v[70:71]\n"
            // ---------- L: L1 finish + acts ----------
            "v_add_f32 v30, v68, v69\n"
            "v_add_f32 v31, v70, v71\n"
            "v_mul_f32 v74, %[nl2e], v30\n"
            "v_mul_f32 v75, %[Ca1], v31\n"
            "v_exp_f32 v74, v74\n"
            "v_exp_f32 v75, v75\n"
            "v_add_f32 v74, 1.0, v74\n"
            "v_add_f32 v75, 1.0, v75\n"
            "v_rcp_f32 v74, v74\n"
            "v_rcp_f32 v75, v75\n"
            "s_nop 0\n"
            "v_fma_f32 v75, %[Aa1], v75, %[Ba1]\n"
            "v_mul_f32 v30, v74, v75\n"                // p1 = i1*g1 (half0)
            // ---------- M: ship p1 ----------
            "ds_swizzle_b32 v78, v30 offset:0x401F\n"
            // h0'/x' landed (allow xr?, p1 outstanding): queue = h0w,h0r*4,xr,p1
            "s_waitcnt lgkmcnt(2)\n"
            // ---------- O: hoisted L0 k0..7 for t+1 (fresh v32-39) ----------
            "v_pk_fma_f32 v[64:65], v[80:81],  v[32:33], v[178:179]\n"
            "v_pk_fma_f32 v[66:67], v[96:97],  v[32:33], v[180:181]\n"
            "v_pk_fma_f32 v[64:65], v[82:83],  v[34:35], v[64:65]\n"
            "v_pk_fma_f32 v[66:67], v[98:99],  v[34:35], v[66:67]\n"
            "v_pk_fma_f32 v[64:65], v[84:85],  v[36:37], v[64:65]\n"
            "v_pk_fma_f32 v[66:67], v[100:101], v[36:37], v[66:67]\n"
            "v_pk_fma_f32 v[64:65], v[86:87],  v[38:39], v[64:65]\n"
            "v_pk_fma_f32 v[66:67], v[102:103], v[38:39], v[66:67]\n"
            // ---------- P/Q: c1 / tanh / h1 on half1 ----------
            "s_waitcnt lgkmcnt(0)\n"                   // p1 (and x') done
            "v_fma_f32 v177, v74, v177, v78\n"         // c1 = f1*c1 + p1
            "v_mul_f32 v29, s21, |v177|\n"
            "v_exp_f32 v29, v29\n"
            "s_nop 0\n"
            "v_add_f32 v29, 1.0, v29\n"
            "v_rcp_f32 v29, v29\n"
            "s_nop 0\n"
            "v_fma_f32 v29, -2.0, v29, 1.0\n"
            "v_bfi_b32 v29, s20, v29, v177\n"
            "v_mul_f32 v29, v75, v29\n"                // h1n = o1*tanh(c1)
            // ---------- R/S: write h1, PREFETCH h1' (v48-63 dead after K) ----------
            "ds_write_b32 v24, v29 offset:64\n"
            "ds_read_b128 v[48:51], v25 offset:64\n"
            "ds_read_b128 v[52:55], v25 offset:80\n"
            "ds_read_b128 v[56:59], v25 offset:96\n"
            "ds_read_b128 v[60:63], v25 offset:112\n"
            // ---------- T: loop ----------
            "s_sub_u32 s22, s22, 1\n"
            "s_cmp_lg_u32 s22, 0\n"
            "s_cbranch_scc1 Llstm_%=\n"
            "s_waitcnt lgkmcnt(0)\n"
            "v_mov_b32 %[c1], v177\n"
            : [c1]"+v"(cs1)
            : [hb]"v"(hb), [xa]"v"(xa), [wb]"v"(wb_),
              [pwa]"v"(pwa), [pwb]"v"(pwb), [pwc]"v"(pwc),
              [bb0a]"v"(bb0a), [bb0b]"v"(bb0b), [bb1a]"v"(bb1a), [bb1b]"v"(bb1b),
              [wxa]"v"(wxa), [wxb]"v"(wxb), [nl2e]"v"(nl2e),
              [Ca1]"v"(Ca1), [Aa1]"v"(Aa1), [Ba1]"v"(Ba1), [c0i]"v"(cs0)
            : "memory", "scc", "s20", "s21", "s22",
              "v24","v25","v26","v27","v28","v29","v30","v31",
              "v32","v33","v34","v35","v36","v37","v38","v39",
              "v40","v41","v42","v43","v44","v45","v46","v47",
              "v48","v49","v50","v51","v52","v53","v54","v55",
              "v56","v57","v58","v59","v60","v61","v62","v63",
              "v64","v65","v66","v67","v68","v69","v70","v71",
              "v72","v73","v74","v75","v76","v77","v78","v79",
              "v80","v81","v82","v83","v84","v85","v86","v87",
              "v88","v89","v90","v91","v92","v93","v94","v95",
              "v96","v97","v98","v99","v100","v101","v102","v103",
              "v104","v105","v106","v107","v108","v109","v110","v111",
              "v112","v113","v114","v115","v116","v117","v118","v119",
              "v120","v121","v122","v123","v124","v125","v126","v127",
              "v128","v129","v130","v131","v132","v133","v134","v135",
              "v136","v137","v138","v139","v140","v141","v142","v143",
              "v144","v145","v146","v147","v148","v149","v150","v151",
              "v152","v153","v154","v155","v156","v157","v158","v159",
              "v160","v161","v162","v163","v164","v165","v166","v167",
              "v168","v169","v170","v171","v172","v173","v174","v175",
              "v176","v177","v178","v179","v180","v181","v182","v183",
              "v184","v185");
    }

    // ---- final L1 step (t=511): recomputed from laundered lane id ----
    {
        int l2 = __builtin_amdgcn_workitem_id_x();
        asm("" : "+v"(l2));                    // block CSE with pre-asm values
        const int grp2  = l2 >> 5;
        const int half2 = (l2 >> 4) & 1;
        const int j2    = l2 & 15;
        const int rb0 = half2 * 16 + j2;
        const int rb1 = rb0 + 32;
        const float Ca2 = half2 ? (-LOG2E) : (-2.0f * LOG2E);
        const float Aa2 = half2 ? 1.0f : 2.0f;
        const float Ba2 = half2 ? 0.0f : -1.0f;

        float a1a = b_ih1[rb0] + b_hh1[rb0];
        float a1b = b_ih1[rb1] + b_hh1[rb1];
        const float* h0p = &lds[grp2 * 40];
        const float* h1p = h0p + 16;
        #pragma unroll
        for (int k = 0; k < 16; ++k) {
            const float h0k = h0p[k], h1k = h1p[k];
            a1a = fmaf(W_ih1[rb0 * 16 + k], h0k, a1a);
            a1b = fmaf(W_ih1[rb1 * 16 + k], h0k, a1b);
            a1a = fmaf(W_hh1[rb0 * 16 + k], h1k, a1a);
            a1b = fmaf(W_hh1[rb1 * 16 + k], h1k, a1b);
        }
        const float s0 = fast_rcp(1.0f + fast_exp2(a1a * (-LOG2E)));            // i1 / f1
        const float s1 = fmaf(Aa2, fast_rcp(1.0f + fast_exp2(a1b * Ca2)), Ba2);  // g1 / o1
        const float p1  = s0 * s1;                    // half0: i1*g1
        const float psw = __shfl_xor(p1, 16);         // half1 receives i1*g1
        const float c1f = fmaf(s0, cs1, psw);         // half1: f1*c1 + i1*g1
        const float e = fast_exp2(fabsf(c1f) * (2.0f * LOG2E));
        float th = fmaf(-2.0f, fast_rcp(e + 1.0f), 1.0f);
        th = copysignf(th, c1f);
        const float h1fin = s1 * th;                  // half1: o1*tanh(c1)

        // FC: out[2*bid+grp] = sum_j h1_j * W_fc[j] + b_fc (per 32-lane group)
        float p = (half2 == 1) ? h1fin * W_fc[j2] : 0.0f;
        p += __shfl_xor(p, 1);
        p += __shfl_xor(p, 2);
        p += __shfl_xor(p, 4);
        p += __shfl_xor(p, 8);
        p += __shfl_xor(p, 16);
        if ((l2 & 31) == 0) out[2 * bid + grp2] = p + b_fc[0];
    }
}

extern "C" void kernel_launch(void* const* d_in, const int* in_sizes, int n_in,
                              void* d_out, int out_size, void* d_ws, size_t ws_size,
                              hipStream_t stream) {
    const float* x     = (const float*)d_in[0];
    const float* W_ih0 = (const float*)d_in[1];
    const float* W_hh0 = (const float*)d_in[2];
    const float* b_ih0 = (const float*)d_in[3];
    const float* b_hh0 = (const float*)d_in[4];
    const float* W_ih1 = (const float*)d_in[5];
    const float* W_hh1 = (const float*)d_in[6];
    const float* b_ih1 = (const float*)d_in[7];
    const float* b_hh1 = (const float*)d_in[8];
    const float* W_fc  = (const float*)d_in[9];
    const float* b_fc  = (const float*)d_in[10];
    float* out = (float*)d_out;

    dim3 grid(2048), block(64);
    hipLaunchKernelGGL(lstm2_wave, grid, block, 0, stream,
                       x, W_ih0, W_hh0, b_ih0, b_hh0,
                       W_ih1, W_hh1, b_ih1, b_hh1, W_fc, b_fc, out);
}

// Round 15
// 224.261 us; speedup vs baseline: 1.0409x; 1.0409x over previous
//
#include <hip/hip_runtime.h>
#include <math.h>

#define TT 512
#define LOG2E 1.4426950408889634f

__device__ __forceinline__ float fast_rcp(float v)  { return __builtin_amdgcn_rcpf(v); }
__device__ __forceinline__ float fast_exp2(float v) { return __builtin_amdgcn_exp2f(v); }

// 2 batches per wave. Lane l: grp=(l>>4)&1 (batch, interleaved by 16),
// half=l>>5 (0: gates i,g ; 1: gates f,o), j=l&15 (unit).
// The i*g -> {f,o}-side crossing is XOR-32, done by ONE
// v_permlane32_swap_b32 (VALU pipe, ~3 cyc; vdst_hi <-> vsrc_lo) instead of
// ds_swizzle xor16 + s_waitcnt lgkmcnt(0) (~60-100 cyc DS round-trip).
// R12 proved h/x read latency was NOT the stall (prefetch: no gain), so the
// two swizzle crossings + their hard waits were the last DS items on the
// 512-step serial chain. Everything else bit-identical to R11 (absmax 0.0).
// (R13 failed compile only: stray ':' on the branch target.)
__global__ __launch_bounds__(64, 2)
void lstm2_wave(const float* __restrict__ x,
                const float* __restrict__ W_ih0, const float* __restrict__ W_hh0,
                const float* __restrict__ b_ih0, const float* __restrict__ b_hh0,
                const float* __restrict__ W_ih1, const float* __restrict__ W_hh1,
                const float* __restrict__ b_ih1, const float* __restrict__ b_hh1,
                const float* __restrict__ W_fc,  const float* __restrict__ b_fc,
                float* __restrict__ out)
{
    const int l    = threadIdx.x;
    const int grp  = (l >> 4) & 1;   // batch within wave (interleaved 16s)
    const int half = l >> 5;         // 0: gates i,g ; 1: gates f,o
    const int j    = l & 15;         // hidden unit
    const int bid  = blockIdx.x;

    const int ra0 = half * 16 + j;   // slot0 row (i or f)
    const int ra1 = ra0 + 32;        // slot1 row (g or o)

    // LDS floats: [0,40) grp0 {h0[16], h1[16], pad8} | [40,80) grp1 | [80,144) trash | [144,1168) x[2][512]
    __shared__ float lds[1168];

    // ---- stage x (2 batches, 1024 floats) coalesced ----
    {
        const float4* xg = (const float4*)(x + (size_t)bid * 1024);
        float4* xl = (float4*)&lds[144];
        xl[l]       = xg[l];
        xl[l + 64]  = xg[l + 64];
        xl[l + 128] = xg[l + 128];
        xl[l + 192] = xg[l + 192];
    }
    __syncthreads();

    const float bb0a = b_ih0[ra0] + b_hh0[ra0];
    const float bb0b = b_ih0[ra1] + b_hh0[ra1];
    const float bb1a = b_ih1[ra0] + b_hh1[ra0];
    const float bb1b = b_ih1[ra1] + b_hh1[ra1];
    const float wxa  = W_ih0[ra0];
    const float wxb  = W_ih0[ra1];
    // slot1 activation consts: half0 -> tanh (g), half1 -> sigmoid (o)
    const float Ca1 = half ? (-LOG2E) : (-2.0f * LOG2E);
    const float Aa1 = half ? 1.0f : 2.0f;
    const float Ba1 = half ? 0.0f : -1.0f;
    const float nl2e = -LOG2E;

    // half1 writes real h; half0 writes trash (all 64 addresses distinct)
    const int widx = half ? (grp * 40 + j) : (80 + grp * 32 + j);

    // ---- peel t = 0 (h,c = 0: gates from bias + x only) ----
    float cs0, cs1 = 0.0f;
    {
        const float x0 = lds[144 + grp * 512];
        const float a_s0 = fmaf(x0, wxa, bb0a);
        const float a_s1 = fmaf(x0, wxb, bb0b);
        const float s0 = fast_rcp(1.0f + fast_exp2(a_s0 * nl2e));                 // i / f
        const float s1 = fmaf(Aa1, fast_rcp(1.0f + fast_exp2(a_s1 * Ca1)), Ba1);  // g / o
        const float p  = s0 * s1;               // half0: i*g
        const float psw = __shfl_xor(p, 32);    // half1 receives i*g
        cs0 = psw;                              // c0 = f*0 + i*g (valid on half1)
        const float e = fast_exp2(fabsf(cs0) * (2.0f * LOG2E));
        float th = fmaf(-2.0f, fast_rcp(e + 1.0f), 1.0f);
        th = copysignf(th, cs0);
        const float h0v = s1 * th;              // half1: o * tanh(c0)
        lds[widx]      = h0v;                   // half0 lands in trash
        lds[widx + 16] = 0.0f;                  // h1 = 0
    }

    // ---- asm loop: t = 1..511. Explicit regs v24-v185. ----
    {
        unsigned base = (unsigned)(size_t)(void*)&lds[0];
        unsigned hb   = base + grp * 160;                 // h read base (bytes)
        unsigned xa   = base + 576 + grp * 2048 + 4;      // &x[grp][1]
        unsigned wb_  = base + widx * 4;                  // write addr
        const float* pwa = W_hh0 + ra0 * 16;              // slot1 row at +2048B
        const float* pwb = W_ih1 + ra0 * 16;
        const float* pwc = W_hh1 + ra0 * 16;

        asm volatile(
            // ---------- prologue ----------
            "s_waitcnt lgkmcnt(0)\n"
            "global_load_dwordx4 v[80:83],   %[pwa], off\n"
            "global_load_dwordx4 v[84:87],   %[pwa], off offset:16\n"
            "global_load_dwordx4 v[88:91],   %[pwa], off offset:32\n"
            "global_load_dwordx4 v[92:95],   %[pwa], off offset:48\n"
            "global_load_dwordx4 v[96:99],   %[pwa], off offset:2048\n"
            "global_load_dwordx4 v[100:103], %[pwa], off offset:2064\n"
            "global_load_dwordx4 v[104:107], %[pwa], off offset:2080\n"
            "global_load_dwordx4 v[108:111], %[pwa], off offset:2096\n"
            "global_load_dwordx4 v[112:115], %[pwb], off\n"
            "global_load_dwordx4 v[116:119], %[pwb], off offset:16\n"
            "global_load_dwordx4 v[120:123], %[pwb], off offset:32\n"
            "global_load_dwordx4 v[124:127], %[pwb], off offset:48\n"
            "global_load_dwordx4 v[128:131], %[pwb], off offset:2048\n"
            "global_load_dwordx4 v[132:135], %[pwb], off offset:2064\n"
            "global_load_dwordx4 v[136:139], %[pwb], off offset:2080\n"
            "global_load_dwordx4 v[140:143], %[pwb], off offset:2096\n"
            "global_load_dwordx4 v[144:147], %[pwc], off\n"
            "global_load_dwordx4 v[148:151], %[pwc], off offset:16\n"
            "global_load_dwordx4 v[152:155], %[pwc], off offset:32\n"
            "global_load_dwordx4 v[156:159], %[pwc], off offset:48\n"
            "global_load_dwordx4 v[160:163], %[pwc], off offset:2048\n"
            "global_load_dwordx4 v[164:167], %[pwc], off offset:2064\n"
            "global_load_dwordx4 v[168:171], %[pwc], off offset:2080\n"
            "global_load_dwordx4 v[172:175], %[pwc], off offset:2096\n"
            "v_mov_b32 v24, %[wb]\n"
            "v_mov_b32 v25, %[hb]\n"
            "v_mov_b32 v26, %[xa]\n"
            "v_mov_b32 v176, %[c0i]\n"
            "v_mov_b32 v177, %[c1]\n"
            "v_mov_b32 v178, %[bb0a]\n"
            "v_mov_b32 v179, 0\n"
            "v_mov_b32 v180, %[bb0b]\n"
            "v_mov_b32 v181, 0\n"
            "v_mov_b32 v182, %[bb1a]\n"
            "v_mov_b32 v183, 0\n"
            "v_mov_b32 v184, %[bb1b]\n"
            "v_mov_b32 v185, 0\n"
            "s_movk_i32 s22, 511\n"
            "s_mov_b32 s20, 0x7fffffff\n"
            "s_mov_b32 s21, 0x4038aa3b\n"       // 2*log2(e)
            "s_waitcnt vmcnt(0)\n"
            "Llstm_%=:\n"
            // ---------- loads (x first for progressive waits) ----------
            "ds_read_b32  v27, v26\n"                  // x[t]
            "ds_read_b128 v[32:35], v25\n"             // h0[0:4)
            "ds_read_b128 v[36:39], v25 offset:16\n"
            "ds_read_b128 v[40:43], v25 offset:32\n"
            "ds_read_b128 v[44:47], v25 offset:48\n"
            "ds_read_b128 v[48:51], v25 offset:64\n"   // h1[0:4)
            "ds_read_b128 v[52:55], v25 offset:80\n"
            "ds_read_b128 v[56:59], v25 offset:96\n"
            "ds_read_b128 v[60:63], v25 offset:112\n"
            "v_add_u32 v26, 4, v26\n"
            // ---------- L0 dots (bias pre-folded in C), progressive waits ----------
            "s_waitcnt lgkmcnt(7)\n"
            "v_pk_fma_f32 v[64:65], v[80:81],  v[32:33], v[178:179]\n"
            "v_pk_fma_f32 v[66:67], v[96:97],  v[32:33], v[180:181]\n"
            "v_pk_fma_f32 v[64:65], v[82:83],  v[34:35], v[64:65]\n"
            "v_pk_fma_f32 v[66:67], v[98:99],  v[34:35], v[66:67]\n"
            "s_waitcnt lgkmcnt(6)\n"
            "v_pk_fma_f32 v[64:65], v[84:85],  v[36:37], v[64:65]\n"
            "v_pk_fma_f32 v[66:67], v[100:101], v[36:37], v[66:67]\n"
            "v_pk_fma_f32 v[64:65], v[86:87],  v[38:39], v[64:65]\n"
            "v_pk_fma_f32 v[66:67], v[102:103], v[38:39], v[66:67]\n"
            "s_waitcnt lgkmcnt(5)\n"
            "v_pk_fma_f32 v[64:65], v[88:89],  v[40:41], v[64:65]\n"
            "v_pk_fma_f32 v[66:67], v[104:105], v[40:41], v[66:67]\n"
            "v_pk_fma_f32 v[64:65], v[90:91],  v[42:43], v[64:65]\n"
            "v_pk_fma_f32 v[66:67], v[106:107], v[42:43], v[66:67]\n"
            "s_waitcnt lgkmcnt(4)\n"
            "v_pk_fma_f32 v[64:65], v[92:93],  v[44:45], v[64:65]\n"
            "v_pk_fma_f32 v[66:67], v[108:109], v[44:45], v[66:67]\n"
            "v_pk_fma_f32 v[64:65], v[94:95],  v[46:47], v[64:65]\n"
            "v_pk_fma_f32 v[66:67], v[110:111], v[46:47], v[66:67]\n"
            // ---------- L0 finish + acts ----------
            "v_add_f32 v28, v64, v65\n"
            "v_add_f32 v29, v66, v67\n"
            "v_fmac_f32 v28, v27, %[wxa]\n"
            "v_fmac_f32 v29, v27, %[wxb]\n"
            "v_mul_f32 v72, %[nl2e], v28\n"
            "v_mul_f32 v73, %[Ca1], v29\n"
            "v_exp_f32 v72, v72\n"
            "v_exp_f32 v73, v73\n"
            "v_add_f32 v72, 1.0, v72\n"
            "v_add_f32 v73, 1.0, v73\n"
            "v_rcp_f32 v72, v72\n"
            "v_rcp_f32 v73, v73\n"
            "s_nop 0\n"
            "v_fma_f32 v73, %[Aa1], v73, %[Ba1]\n"
            "v_mul_f32 v28, v72, v73\n"                // p0 = i0*g0 (half0)
            // ---------- ship p0 to half1 via VALU lane swap (v76_hi <- v28_lo) ----------
            "s_nop 0\n"
            "v_permlane32_swap_b32 v76, v28\n"
            // ---------- L1 dots part A (wb x h0) ----------
            "v_pk_fma_f32 v[68:69], v[112:113], v[32:33], v[182:183]\n"
            "v_pk_fma_f32 v[70:71], v[128:129], v[32:33], v[184:185]\n"
            "v_pk_fma_f32 v[68:69], v[114:115], v[34:35], v[68:69]\n"
            "v_pk_fma_f32 v[70:71], v[130:131], v[34:35], v[70:71]\n"
            "v_pk_fma_f32 v[68:69], v[116:117], v[36:37], v[68:69]\n"
            "v_pk_fma_f32 v[70:71], v[132:133], v[36:37], v[70:71]\n"
            "v_pk_fma_f32 v[68:69], v[118:119], v[38:39], v[68:69]\n"
            "v_pk_fma_f32 v[70:71], v[134:135], v[38:39], v[70:71]\n"
            "v_pk_fma_f32 v[68:69], v[120:121], v[40:41], v[68:69]\n"
            "v_pk_fma_f32 v[70:71], v[136:137], v[40:41], v[70:71]\n"
            "v_pk_fma_f32 v[68:69], v[122:123], v[42:43], v[68:69]\n"
            "v_pk_fma_f32 v[70:71], v[138:139], v[42:43], v[70:71]\n"
            "v_pk_fma_f32 v[68:69], v[124:125], v[44:45], v[68:69]\n"
            "v_pk_fma_f32 v[70:71], v[140:141], v[44:45], v[70:71]\n"
            "v_pk_fma_f32 v[68:69], v[126:127], v[46:47], v[68:69]\n"
            "v_pk_fma_f32 v[70:71], v[142:143], v[46:47], v[70:71]\n"
            // ---------- L0 state on half1: c0 = f0*c0 + p0; h0 = o0*tanh(c0) ----------
            "s_waitcnt lgkmcnt(0)\n"                   // h1 reads done (for partB)
            "v_fma_f32 v176, v72, v176, v76\n"
            "v_mul_f32 v29, s21, |v176|\n"
            "v_exp_f32 v29, v29\n"
            "s_nop 0\n"
            "v_add_f32 v29, 1.0, v29\n"
            "v_rcp_f32 v29, v29\n"
            "s_nop 0\n"
            "v_fma_f32 v29, -2.0, v29, 1.0\n"
            "v_bfi_b32 v29, s20, v29, v176\n"
            "v_mul_f32 v28, v73, v29\n"                // h0n (half1: v73 = o0)
            "ds_write_b32 v24, v28\n"
            // ---------- L1 dots part B (wc x h1) ----------
            "v_pk_fma_f32 v[68:69], v[144:145], v[48:49], v[68:69]\n"
            "v_pk_fma_f32 v[70:71], v[160:161], v[48:49], v[70:71]\n"
            "v_pk_fma_f32 v[68:69], v[146:147], v[50:51], v[68:69]\n"
            "v_pk_fma_f32 v[70:71], v[162:163], v[50:51], v[70:71]\n"
            "v_pk_fma_f32 v[68:69], v[148:149], v[52:53], v[68:69]\n"
            "v_pk_fma_f32 v[70:71], v[164:165], v[52:53], v[70:71]\n"
            "v_pk_fma_f32 v[68:69], v[150:151], v[54:55], v[68:69]\n"
            "v_pk_fma_f32 v[70:71], v[166:167], v[54:55], v[70:71]\n"
            "v_pk_fma_f32 v[68:69], v[152:153], v[56:57], v[68:69]\n"
            "v_pk_fma_f32 v[70:71], v[168:169], v[56:57], v[70:71]\n"
            "v_pk_fma_f32 v[68:69], v[154:155], v[58:59], v[68:69]\n"
            "v_pk_fma_f32 v[70:71], v[170:171], v[58:59], v[70:71]\n"
            "v_pk_fma_f32 v[68:69], v[156:157], v[60:61], v[68:69]\n"
            "v_pk_fma_f32 v[70:71], v[172:173], v[60:61], v[70:71]\n"
            "v_pk_fma_f32 v[68:69], v[158:159], v[62:63], v[68:69]\n"
            "v_pk_fma_f32 v[70:71], v[174:175], v[62:63], v[70:71]\n"
            // ---------- L1 finish + acts ----------
            "v_add_f32 v30, v68, v69\n"
            "v_add_f32 v31, v70, v71\n"
            "v_mul_f32 v74, %[nl2e], v30\n"
            "v_mul_f32 v75, %[Ca1], v31\n"
            "v_exp_f32 v74, v74\n"
            "v_exp_f32 v75, v75\n"
            "v_add_f32 v74, 1.0, v74\n"
            "v_add_f32 v75, 1.0, v75\n"
            "v_rcp_f32 v74, v74\n"
            "v_rcp_f32 v75, v75\n"
            "s_nop 0\n"
            "v_fma_f32 v75, %[Aa1], v75, %[Ba1]\n"
            "v_mul_f32 v30, v74, v75\n"                // p1 = i1*g1 (half0)
            // ---------- ship p1 via VALU lane swap (no DS, no waitcnt) ----------
            "s_nop 0\n"
            "v_permlane32_swap_b32 v78, v30\n"
            // ---------- L1 state on half1 ----------
            "v_fma_f32 v177, v74, v177, v78\n"         // c1 = f1*c1 + p1
            "v_mul_f32 v29, s21, |v177|\n"
            "v_exp_f32 v29, v29\n"
            "s_nop 0\n"
            "v_add_f32 v29, 1.0, v29\n"
            "v_rcp_f32 v29, v29\n"
            "s_nop 0\n"
            "v_fma_f32 v29, -2.0, v29, 1.0\n"
            "v_bfi_b32 v29, s20, v29, v177\n"
            "v_mul_f32 v29, v75, v29\n"                // h1n = o1*tanh(c1)
            "ds_write_b32 v24, v29 offset:64\n"
            // ---------- loop ----------
            "s_sub_u32 s22, s22, 1\n"
            "s_cmp_lg_u32 s22, 0\n"
            "s_cbranch_scc1 Llstm_%=\n"
            "s_waitcnt lgkmcnt(0)\n"
            "v_mov_b32 %[c1], v177\n"
            : [c1]"+v"(cs1)
            : [hb]"v"(hb), [xa]"v"(xa), [wb]"v"(wb_),
              [pwa]"v"(pwa), [pwb]"v"(pwb), [pwc]"v"(pwc),
              [bb0a]"v"(bb0a), [bb0b]"v"(bb0b), [bb1a]"v"(bb1a), [bb1b]"v"(bb1b),
              [wxa]"v"(wxa), [wxb]"v"(wxb), [nl2e]"v"(nl2e),
              [Ca1]"v"(Ca1), [Aa1]"v"(Aa1), [Ba1]"v"(Ba1), [c0i]"v"(cs0)
            : "memory", "scc", "s20", "s21", "s22",
              "v24","v25","v26","v27","v28","v29","v30","v31",
              "v32","v33","v34","v35","v36","v37","v38","v39",
              "v40","v41","v42","v43","v44","v45","v46","v47",
              "v48","v49","v50","v51","v52","v53","v54","v55",
              "v56","v57","v58","v59","v60","v61","v62","v63",
              "v64","v65","v66","v67","v68","v69","v70","v71",
              "v72","v73","v74","v75","v76","v77","v78","v79",
              "v80","v81","v82","v83","v84","v85","v86","v87",
              "v88","v89","v90","v91","v92","v93","v94","v95",
              "v96","v97","v98","v99","v100","v101","v102","v103",
              "v104","v105","v106","v107","v108","v109","v110","v111",
              "v112","v113","v114","v115","v116","v117","v118","v119",
              "v120","v121","v122","v123","v124","v125","v126","v127",
              "v128","v129","v130","v131","v132","v133","v134","v135",
              "v136","v137","v138","v139","v140","v141","v142","v143",
              "v144","v145","v146","v147","v148","v149","v150","v151",
              "v152","v153","v154","v155","v156","v157","v158","v159",
              "v160","v161","v162","v163","v164","v165","v166","v167",
              "v168","v169","v170","v171","v172","v173","v174","v175",
              "v176","v177","v178","v179","v180","v181","v182","v183",
              "v184","v185");
    }

    // ---- final L1 step (t=511): recomputed from laundered lane id ----
    {
        int l2 = __builtin_amdgcn_workitem_id_x();
        asm("" : "+v"(l2));                    // block CSE with pre-asm values
        const int grp2  = (l2 >> 4) & 1;
        const int half2 = l2 >> 5;
        const int j2    = l2 & 15;
        const int rb0 = half2 * 16 + j2;
        const int rb1 = rb0 + 32;
        const float Ca2 = half2 ? (-LOG2E) : (-2.0f * LOG2E);
        const float Aa2 = half2 ? 1.0f : 2.0f;
        const float Ba2 = half2 ? 0.0f : -1.0f;

        float a1a = b_ih1[rb0] + b_hh1[rb0];
        float a1b = b_ih1[rb1] + b_hh1[rb1];
        const float* h0p = &lds[grp2 * 40];
        const float* h1p = h0p + 16;
        #pragma unroll
        for (int k = 0; k < 16; ++k) {
            const float h0k = h0p[k], h1k = h1p[k];
            a1a = fmaf(W_ih1[rb0 * 16 + k], h0k, a1a);
            a1b = fmaf(W_ih1[rb1 * 16 + k], h0k, a1b);
            a1a = fmaf(W_hh1[rb0 * 16 + k], h1k, a1a);
            a1b = fmaf(W_hh1[rb1 * 16 + k], h1k, a1b);
        }
        const float s0 = fast_rcp(1.0f + fast_exp2(a1a * (-LOG2E)));            // i1 / f1
        const float s1 = fmaf(Aa2, fast_rcp(1.0f + fast_exp2(a1b * Ca2)), Ba2);  // g1 / o1
        const float p1  = s0 * s1;                    // half0: i1*g1
        const float psw = __shfl_xor(p1, 32);         // half1 receives i1*g1
        const float c1f = fmaf(s0, cs1, psw);         // half1: f1*c1 + i1*g1
        const float e = fast_exp2(fabsf(c1f) * (2.0f * LOG2E));
        float th = fmaf(-2.0f, fast_rcp(e + 1.0f), 1.0f);
        th = copysignf(th, c1f);
        const float h1fin = s1 * th;                  // half1: o1*tanh(c1)

        // FC: out[2*bid+grp] = sum_j h1_j * W_fc[j] + b_fc
        float p = (half2 == 1) ? h1fin * W_fc[j2] : 0.0f;
        p += __shfl_xor(p, 1);
        p += __shfl_xor(p, 2);
        p += __shfl_xor(p, 4);
        p += __shfl_xor(p, 8);
        if (l2 >= 32 && (l2 & 15) == 0) out[2 * bid + grp2] = p + b_fc[0];
    }
}

extern "C" void kernel_launch(void* const* d_in, const int* in_sizes, int n_in,
                              void* d_out, int out_size, void* d_ws, size_t ws_size,
                              hipStream_t stream) {
    const float* x     = (const float*)d_in[0];
    const float* W_ih0 = (const float*)d_in[1];
    const float* W_hh0 = (const float*)d_in[2];
    const float* b_ih0 = (const float*)d_in[3];
    const float* b_hh0 = (const float*)d_in[4];
    const float* W_ih1 = (const float*)d_in[5];
    const float* W_hh1 = (const float*)d_in[6];
    const float* b_ih1 = (const float*)d_in[7];
    const float* b_hh1 = (const float*)d_in[8];
    const float* W_fc  = (const float*)d_in[9];
    const float* b_fc  = (const float*)d_in[10];
    float* out = (float*)d_out;

    dim3 grid(2048), block(64);
    hipLaunchKernelGGL(lstm2_wave, grid, block, 0, stream,
                       x, W_ih0, W_hh0, b_ih0, b_hh0,
                       W_ih1, W_hh1, b_ih1, b_hh1, W_fc, b_fc, out);
}

// Round 16
// 219.823 us; speedup vs baseline: 1.0619x; 1.0202x over previous
//
#include <hip/hip_runtime.h>
#include <math.h>

#define TT 512
#define LOG2E 1.4426950408889634f

__device__ __forceinline__ float fast_rcp(float v)  { return __builtin_amdgcn_rcpf(v); }
__device__ __forceinline__ float fast_exp2(float v) { return __builtin_amdgcn_exp2f(v); }

// 2 batches per wave. Lane l: grp=(l>>4)&1, half=l>>5 (0: i,g ; 1: f,o), j=l&15.
// i*g crossing via v_permlane32_swap_b32 (VALU, no DS wait) -- R14-verified.
// R15: (a) bank-conflict-free write layout (all h/trash writes exactly 2-way,
// grp h-stride 48 floats so the two broadcast-read bases hit banks 0 vs 16),
// (b) unroll-4 with batched x reads (2x ds_read2_b32 per 4 steps replaces 4x
// ds_read_b32 + 4x addr-add). Substep arithmetic bit-identical to R14.
#define SUBSTEP(XR) \
            "ds_read_b128 v[32:35], v25\n"             \
            "ds_read_b128 v[36:39], v25 offset:16\n"   \
            "ds_read_b128 v[40:43], v25 offset:32\n"   \
            "ds_read_b128 v[44:47], v25 offset:48\n"   \
            "ds_read_b128 v[48:51], v25 offset:64\n"   \
            "ds_read_b128 v[52:55], v25 offset:80\n"   \
            "ds_read_b128 v[56:59], v25 offset:96\n"   \
            "ds_read_b128 v[60:63], v25 offset:112\n"  \
            "s_waitcnt lgkmcnt(7)\n"                                           \
            "v_pk_fma_f32 v[64:65], v[80:81],  v[32:33], v[178:179]\n"         \
            "v_pk_fma_f32 v[66:67], v[96:97],  v[32:33], v[180:181]\n"         \
            "v_pk_fma_f32 v[64:65], v[82:83],  v[34:35], v[64:65]\n"           \
            "v_pk_fma_f32 v[66:67], v[98:99],  v[34:35], v[66:67]\n"           \
            "s_waitcnt lgkmcnt(6)\n"                                           \
            "v_pk_fma_f32 v[64:65], v[84:85],  v[36:37], v[64:65]\n"           \
            "v_pk_fma_f32 v[66:67], v[100:101], v[36:37], v[66:67]\n"          \
            "v_pk_fma_f32 v[64:65], v[86:87],  v[38:39], v[64:65]\n"           \
            "v_pk_fma_f32 v[66:67], v[102:103], v[38:39], v[66:67]\n"          \
            "s_waitcnt lgkmcnt(5)\n"                                           \
            "v_pk_fma_f32 v[64:65], v[88:89],  v[40:41], v[64:65]\n"           \
            "v_pk_fma_f32 v[66:67], v[104:105], v[40:41], v[66:67]\n"          \
            "v_pk_fma_f32 v[64:65], v[90:91],  v[42:43], v[64:65]\n"           \
            "v_pk_fma_f32 v[66:67], v[106:107], v[42:43], v[66:67]\n"          \
            "s_waitcnt lgkmcnt(4)\n"                                           \
            "v_pk_fma_f32 v[64:65], v[92:93],  v[44:45], v[64:65]\n"           \
            "v_pk_fma_f32 v[66:67], v[108:109], v[44:45], v[66:67]\n"          \
            "v_pk_fma_f32 v[64:65], v[94:95],  v[46:47], v[64:65]\n"           \
            "v_pk_fma_f32 v[66:67], v[110:111], v[46:47], v[66:67]\n"          \
            "v_add_f32 v28, v64, v65\n"                                        \
            "v_add_f32 v29, v66, v67\n"                                        \
            "v_fmac_f32 v28, " XR ", %[wxa]\n"                                 \
            "v_fmac_f32 v29, " XR ", %[wxb]\n"                                 \
            "v_mul_f32 v72, %[nl2e], v28\n"                                    \
            "v_mul_f32 v73, %[Ca1], v29\n"                                     \
            "v_exp_f32 v72, v72\n"                                             \
            "v_exp_f32 v73, v73\n"                                             \
            "v_add_f32 v72, 1.0, v72\n"                                        \
            "v_add_f32 v73, 1.0, v73\n"                                        \
            "v_rcp_f32 v72, v72\n"                                             \
            "v_rcp_f32 v73, v73\n"                                             \
            "s_nop 0\n"                                                        \
            "v_fma_f32 v73, %[Aa1], v73, %[Ba1]\n"                             \
            "v_mul_f32 v28, v72, v73\n"                                        \
            "s_nop 0\n"                                                        \
            "v_permlane32_swap_b32 v76, v28\n"                                 \
            "v_pk_fma_f32 v[68:69], v[112:113], v[32:33], v[182:183]\n"        \
            "v_pk_fma_f32 v[70:71], v[128:129], v[32:33], v[184:185]\n"        \
            "v_pk_fma_f32 v[68:69], v[114:115], v[34:35], v[68:69]\n"          \
            "v_pk_fma_f32 v[70:71], v[130:131], v[34:35], v[70:71]\n"          \
            "v_pk_fma_f32 v[68:69], v[116:117], v[36:37], v[68:69]\n"          \
            "v_pk_fma_f32 v[70:71], v[132:133], v[36:37], v[70:71]\n"          \
            "v_pk_fma_f32 v[68:69], v[118:119], v[38:39], v[68:69]\n"          \
            "v_pk_fma_f32 v[70:71], v[134:135], v[38:39], v[70:71]\n"          \
            "v_pk_fma_f32 v[68:69], v[120:121], v[40:41], v[68:69]\n"          \
            "v_pk_fma_f32 v[70:71], v[136:137], v[40:41], v[70:71]\n"          \
            "v_pk_fma_f32 v[68:69], v[122:123], v[42:43], v[68:69]\n"          \
            "v_pk_fma_f32 v[70:71], v[138:139], v[42:43], v[70:71]\n"          \
            "v_pk_fma_f32 v[68:69], v[124:125], v[44:45], v[68:69]\n"          \
            "v_pk_fma_f32 v[70:71], v[140:141], v[44:45], v[70:71]\n"          \
            "v_pk_fma_f32 v[68:69], v[126:127], v[46:47], v[68:69]\n"          \
            "v_pk_fma_f32 v[70:71], v[142:143], v[46:47], v[70:71]\n"          \
            "s_waitcnt lgkmcnt(0)\n"                                           \
            "v_fma_f32 v176, v72, v176, v76\n"                                 \
            "v_mul_f32 v29, s21, |v176|\n"                                     \
            "v_exp_f32 v29, v29\n"                                             \
            "s_nop 0\n"                                                        \
            "v_add_f32 v29, 1.0, v29\n"                                        \
            "v_rcp_f32 v29, v29\n"                                             \
            "s_nop 0\n"                                                        \
            "v_fma_f32 v29, -2.0, v29, 1.0\n"                                  \
            "v_bfi_b32 v29, s20, v29, v176\n"                                  \
            "v_mul_f32 v28, v73, v29\n"                                        \
            "ds_write_b32 v24, v28\n"                                          \
            "v_pk_fma_f32 v[68:69], v[144:145], v[48:49], v[68:69]\n"          \
            "v_pk_fma_f32 v[70:71], v[160:161], v[48:49], v[70:71]\n"          \
            "v_pk_fma_f32 v[68:69], v[146:147], v[50:51], v[68:69]\n"          \
            "v_pk_fma_f32 v[70:71], v[162:163], v[50:51], v[70:71]\n"          \
            "v_pk_fma_f32 v[68:69], v[148:149], v[52:53], v[68:69]\n"          \
            "v_pk_fma_f32 v[70:71], v[164:165], v[52:53], v[70:71]\n"          \
            "v_pk_fma_f32 v[68:69], v[150:151], v[54:55], v[68:69]\n"          \
            "v_pk_fma_f32 v[70:71], v[166:167], v[54:55], v[70:71]\n"          \
            "v_pk_fma_f32 v[68:69], v[152:153], v[56:57], v[68:69]\n"          \
            "v_pk_fma_f32 v[70:71], v[168:169], v[56:57], v[70:71]\n"          \
            "v_pk_fma_f32 v[68:69], v[154:155], v[58:59], v[68:69]\n"          \
            "v_pk_fma_f32 v[70:71], v[170:171], v[58:59], v[70:71]\n"          \
            "v_pk_fma_f32 v[68:69], v[156:157], v[60:61], v[68:69]\n"          \
            "v_pk_fma_f32 v[70:71], v[172:173], v[60:61], v[70:71]\n"          \
            "v_pk_fma_f32 v[68:69], v[158:159], v[62:63], v[68:69]\n"          \
            "v_pk_fma_f32 v[70:71], v[174:175], v[62:63], v[70:71]\n"          \
            "v_add_f32 v30, v68, v69\n"                                        \
            "v_add_f32 v31, v70, v71\n"                                        \
            "v_mul_f32 v74, %[nl2e], v30\n"                                    \
            "v_mul_f32 v75, %[Ca1], v31\n"                                     \
            "v_exp_f32 v74, v74\n"                                             \
            "v_exp_f32 v75, v75\n"                                             \
            "v_add_f32 v74, 1.0, v74\n"                                        \
            "v_add_f32 v75, 1.0, v75\n"                                        \
            "v_rcp_f32 v74, v74\n"                                             \
            "v_rcp_f32 v75, v75\n"                                             \
            "s_nop 0\n"                                                        \
            "v_fma_f32 v75, %[Aa1], v75, %[Ba1]\n"                             \
            "v_mul_f32 v30, v74, v75\n"                                        \
            "s_nop 0\n"                                                        \
            "v_permlane32_swap_b32 v78, v30\n"                                 \
            "v_fma_f32 v177, v74, v177, v78\n"                                 \
            "v_mul_f32 v29, s21, |v177|\n"                                     \
            "v_exp_f32 v29, v29\n"                                             \
            "s_nop 0\n"                                                        \
            "v_add_f32 v29, 1.0, v29\n"                                        \
            "v_rcp_f32 v29, v29\n"                                             \
            "s_nop 0\n"                                                        \
            "v_fma_f32 v29, -2.0, v29, 1.0\n"                                  \
            "v_bfi_b32 v29, s20, v29, v177\n"                                  \
            "v_mul_f32 v29, v75, v29\n"                                        \
            "ds_write_b32 v24, v29 offset:64\n"

__global__ __launch_bounds__(64, 2)
void lstm2_wave(const float* __restrict__ x,
                const float* __restrict__ W_ih0, const float* __restrict__ W_hh0,
                const float* __restrict__ b_ih0, const float* __restrict__ b_hh0,
                const float* __restrict__ W_ih1, const float* __restrict__ W_hh1,
                const float* __restrict__ b_ih1, const float* __restrict__ b_hh1,
                const float* __restrict__ W_fc,  const float* __restrict__ b_fc,
                float* __restrict__ out)
{
    const int l    = threadIdx.x;
    const int grp  = (l >> 4) & 1;   // batch within wave (interleaved 16s)
    const int half = l >> 5;         // 0: gates i,g ; 1: gates f,o
    const int j    = l & 15;         // hidden unit
    const int bid  = blockIdx.x;

    const int ra0 = half * 16 + j;   // slot0 row (i or f)
    const int ra1 = ra0 + 32;        // slot1 row (g or o)

    // LDS floats: grp0 h [0,32) | grp1 h [48,80) | trash [120,168)
    //             | x grp0 [168,680) | x grp1 [688,1200)
    // Write-bank audit: every h/trash write hits each bank exactly 2x (free);
    // grp broadcast-read bases on banks 0 vs 16; x reads 8 banks apart.
    __shared__ float lds[1200];

    // ---- stage x (2 batches) coalesced ----
    {
        const float4* xg = (const float4*)(x + (size_t)bid * 1024);
        float4* x0 = (float4*)&lds[168];
        float4* x1 = (float4*)&lds[688];
        x0[l]      = xg[l];
        x0[l + 64] = xg[l + 64];
        x1[l]      = xg[128 + l];
        x1[l + 64] = xg[192 + l];
    }
    __syncthreads();

    const float bb0a = b_ih0[ra0] + b_hh0[ra0];
    const float bb0b = b_ih0[ra1] + b_hh0[ra1];
    const float bb1a = b_ih1[ra0] + b_hh1[ra0];
    const float bb1b = b_ih1[ra1] + b_hh1[ra1];
    const float wxa  = W_ih0[ra0];
    const float wxb  = W_ih0[ra1];
    const float Ca1 = half ? (-LOG2E) : (-2.0f * LOG2E);
    const float Aa1 = half ? 1.0f : 2.0f;
    const float Ba1 = half ? 0.0f : -1.0f;
    const float nl2e = -LOG2E;

    // half1 writes real h (grp*48+j); half0 writes trash (120+grp*16+j)
    const int widx = half ? (grp * 48 + j) : (120 + grp * 16 + j);

    // ---- peel t = 0 (h,c = 0) ----
    float cs0, cs1 = 0.0f;
    {
        const float x0v = lds[168 + grp * 520];
        const float a_s0 = fmaf(x0v, wxa, bb0a);
        const float a_s1 = fmaf(x0v, wxb, bb0b);
        const float s0 = fast_rcp(1.0f + fast_exp2(a_s0 * nl2e));                 // i / f
        const float s1 = fmaf(Aa1, fast_rcp(1.0f + fast_exp2(a_s1 * Ca1)), Ba1);  // g / o
        const float p  = s0 * s1;               // half0: i*g
        const float psw = __shfl_xor(p, 32);    // half1 receives i*g
        cs0 = psw;
        const float e = fast_exp2(fabsf(cs0) * (2.0f * LOG2E));
        float th = fmaf(-2.0f, fast_rcp(e + 1.0f), 1.0f);
        th = copysignf(th, cs0);
        const float h0v = s1 * th;              // half1: o * tanh(c0)
        lds[widx]      = h0v;
        lds[widx + 16] = 0.0f;                  // h1 = 0
    }

    // ---- asm: 127 unrolled-4 iterations (t=1..508) + 3-step tail (t=509..511) ----
    {
        unsigned base = (unsigned)(size_t)(void*)&lds[0];
        unsigned hb   = base + grp * 192;                     // h read base
        unsigned xa   = base + (168 + grp * 520 + 1) * 4;     // &x[grp][1]
        unsigned wb_  = base + widx * 4;
        const float* pwa = W_hh0 + ra0 * 16;
        const float* pwb = W_ih1 + ra0 * 16;
        const float* pwc = W_hh1 + ra0 * 16;

        asm volatile(
            // ---------- prologue ----------
            "s_waitcnt lgkmcnt(0)\n"
            "global_load_dwordx4 v[80:83],   %[pwa], off\n"
            "global_load_dwordx4 v[84:87],   %[pwa], off offset:16\n"
            "global_load_dwordx4 v[88:91],   %[pwa], off offset:32\n"
            "global_load_dwordx4 v[92:95],   %[pwa], off offset:48\n"
            "global_load_dwordx4 v[96:99],   %[pwa], off offset:2048\n"
            "global_load_dwordx4 v[100:103], %[pwa], off offset:2064\n"
            "global_load_dwordx4 v[104:107], %[pwa], off offset:2080\n"
            "global_load_dwordx4 v[108:111], %[pwa], off offset:2096\n"
            "global_load_dwordx4 v[112:115], %[pwb], off\n"
            "global_load_dwordx4 v[116:119], %[pwb], off offset:16\n"
            "global_load_dwordx4 v[120:123], %[pwb], off offset:32\n"
            "global_load_dwordx4 v[124:127], %[pwb], off offset:48\n"
            "global_load_dwordx4 v[128:131], %[pwb], off offset:2048\n"
            "global_load_dwordx4 v[132:135], %[pwb], off offset:2064\n"
            "global_load_dwordx4 v[136:139], %[pwb], off offset:2080\n"
            "global_load_dwordx4 v[140:143], %[pwb], off offset:2096\n"
            "global_load_dwordx4 v[144:147], %[pwc], off\n"
            "global_load_dwordx4 v[148:151], %[pwc], off offset:16\n"
            "global_load_dwordx4 v[152:155], %[pwc], off offset:32\n"
            "global_load_dwordx4 v[156:159], %[pwc], off offset:48\n"
            "global_load_dwordx4 v[160:163], %[pwc], off offset:2048\n"
            "global_load_dwordx4 v[164:167], %[pwc], off offset:2064\n"
            "global_load_dwordx4 v[168:171], %[pwc], off offset:2080\n"
            "global_load_dwordx4 v[172:175], %[pwc], off offset:2096\n"
            "v_mov_b32 v24, %[wb]\n"
            "v_mov_b32 v25, %[hb]\n"
            "v_mov_b32 v26, %[xa]\n"
            "v_mov_b32 v176, %[c0i]\n"
            "v_mov_b32 v177, %[c1]\n"
            "v_mov_b32 v178, %[bb0a]\n"
            "v_mov_b32 v179, 0\n"
            "v_mov_b32 v180, %[bb0b]\n"
            "v_mov_b32 v181, 0\n"
            "v_mov_b32 v182, %[bb1a]\n"
            "v_mov_b32 v183, 0\n"
            "v_mov_b32 v184, %[bb1b]\n"
            "v_mov_b32 v185, 0\n"
            "s_movk_i32 s22, 127\n"
            "s_mov_b32 s20, 0x7fffffff\n"
            "s_mov_b32 s21, 0x4038aa3b\n"       // 2*log2(e)
            "s_waitcnt vmcnt(0)\n"
            "Llstm_%=:\n"
            "ds_read2_b32 v[186:187], v26 offset0:0 offset1:1\n"
            "ds_read2_b32 v[188:189], v26 offset0:2 offset1:3\n"
            "v_add_u32 v26, 16, v26\n"
            SUBSTEP("v186")
            SUBSTEP("v187")
            SUBSTEP("v188")
            SUBSTEP("v189")
            "s_sub_u32 s22, s22, 1\n"
            "s_cmp_lg_u32 s22, 0\n"
            "s_cbranch_scc1 Llstm_%=\n"
            // ---------- tail: t = 509, 510, 511 ----------
            "ds_read2_b32 v[186:187], v26 offset0:0 offset1:1\n"
            "ds_read_b32  v188, v26 offset:8\n"
            SUBSTEP("v186")
            SUBSTEP("v187")
            SUBSTEP("v188")
            "s_waitcnt lgkmcnt(0)\n"
            "v_mov_b32 %[c1], v177\n"
            : [c1]"+v"(cs1)
            : [hb]"v"(hb), [xa]"v"(xa), [wb]"v"(wb_),
              [pwa]"v"(pwa), [pwb]"v"(pwb), [pwc]"v"(pwc),
              [bb0a]"v"(bb0a), [bb0b]"v"(bb0b), [bb1a]"v"(bb1a), [bb1b]"v"(bb1b),
              [wxa]"v"(wxa), [wxb]"v"(wxb), [nl2e]"v"(nl2e),
              [Ca1]"v"(Ca1), [Aa1]"v"(Aa1), [Ba1]"v"(Ba1), [c0i]"v"(cs0)
            : "memory", "scc", "s20", "s21", "s22",
              "v24","v25","v26","v27","v28","v29","v30","v31",
              "v32","v33","v34","v35","v36","v37","v38","v39",
              "v40","v41","v42","v43","v44","v45","v46","v47",
              "v48","v49","v50","v51","v52","v53","v54","v55",
              "v56","v57","v58","v59","v60","v61","v62","v63",
              "v64","v65","v66","v67","v68","v69","v70","v71",
              "v72","v73","v74","v75","v76","v77","v78","v79",
              "v80","v81","v82","v83","v84","v85","v86","v87",
              "v88","v89","v90","v91","v92","v93","v94","v95",
              "v96","v97","v98","v99","v100","v101","v102","v103",
              "v104","v105","v106","v107","v108","v109","v110","v111",
              "v112","v113","v114","v115","v116","v117","v118","v119",
              "v120","v121","v122","v123","v124","v125","v126","v127",
              "v128","v129","v130","v131","v132","v133","v134","v135",
              "v136","v137","v138","v139","v140","v141","v142","v143",
              "v144","v145","v146","v147","v148","v149","v150","v151",
              "v152","v153","v154","v155","v156","v157","v158","v159",
              "v160","v161","v162","v163","v164","v165","v166","v167",
              "v168","v169","v170","v171","v172","v173","v174","v175",
              "v176","v177","v178","v179","v180","v181","v182","v183",
              "v184","v185","v186","v187","v188","v189");
    }

    // ---- final L1 step (t=511): recomputed from laundered lane id ----
    {
        int l2 = __builtin_amdgcn_workitem_id_x();
        asm("" : "+v"(l2));                    // block CSE with pre-asm values
        const int grp2  = (l2 >> 4) & 1;
        const int half2 = l2 >> 5;
        const int j2    = l2 & 15;
        const int rb0 = half2 * 16 + j2;
        const int rb1 = rb0 + 32;
        const float Ca2 = half2 ? (-LOG2E) : (-2.0f * LOG2E);
        const float Aa2 = half2 ? 1.0f : 2.0f;
        const float Ba2 = half2 ? 0.0f : -1.0f;

        float a1a = b_ih1[rb0] + b_hh1[rb0];
        float a1b = b_ih1[rb1] + b_hh1[rb1];
        const float* h0p = &lds[grp2 * 48];
        const float* h1p = h0p + 16;
        #pragma unroll
        for (int k = 0; k < 16; ++k) {
            const float h0k = h0p[k], h1k = h1p[k];
            a1a = fmaf(W_ih1[rb0 * 16 + k], h0k, a1a);
            a1b = fmaf(W_ih1[rb1 * 16 + k], h0k, a1b);
            a1a = fmaf(W_hh1[rb0 * 16 + k], h1k, a1a);
            a1b = fmaf(W_hh1[rb1 * 16 + k], h1k, a1b);
        }
        const float s0 = fast_rcp(1.0f + fast_exp2(a1a * (-LOG2E)));            // i1 / f1
        const float s1 = fmaf(Aa2, fast_rcp(1.0f + fast_exp2(a1b * Ca2)), Ba2);  // g1 / o1
        const float p1  = s0 * s1;                    // half0: i1*g1
        const float psw = __shfl_xor(p1, 32);         // half1 receives i1*g1
        const float c1f = fmaf(s0, cs1, psw);         // half1: f1*c1 + i1*g1
        const float e = fast_exp2(fabsf(c1f) * (2.0f * LOG2E));
        float th = fmaf(-2.0f, fast_rcp(e + 1.0f), 1.0f);
        th = copysignf(th, c1f);
        const float h1fin = s1 * th;                  // half1: o1*tanh(c1)

        // FC: out[2*bid+grp] = sum_j h1_j * W_fc[j] + b_fc
        float p = (half2 == 1) ? h1fin * W_fc[j2] : 0.0f;
        p += __shfl_xor(p, 1);
        p += __shfl_xor(p, 2);
        p += __shfl_xor(p, 4);
        p += __shfl_xor(p, 8);
        if (l2 >= 32 && (l2 & 15) == 0) out[2 * bid + grp2] = p + b_fc[0];
    }
}

extern "C" void kernel_launch(void* const* d_in, const int* in_sizes, int n_in,
                              void* d_out, int out_size, void* d_ws, size_t ws_size,
                              hipStream_t stream) {
    const float* x     = (const float*)d_in[0];
    const float* W_ih0 = (const float*)d_in[1];
    const float* W_hh0 = (const float*)d_in[2];
    const float* b_ih0 = (const float*)d_in[3];
    const float* b_hh0 = (const float*)d_in[4];
    const float* W_ih1 = (const float*)d_in[5];
    const float* W_hh1 = (const float*)d_in[6];
    const float* b_ih1 = (const float*)d_in[7];
    const float* b_hh1 = (const float*)d_in[8];
    const float* W_fc  = (const float*)d_in[9];
    const float* b_fc  = (const float*)d_in[10];
    float* out = (float*)d_out;

    dim3 grid(2048), block(64);
    hipLaunchKernelGGL(lstm2_wave, grid, block, 0, stream,
                       x, W_ih0, W_hh0, b_ih0, b_hh0,
                       W_ih1, W_hh1, b_ih1, b_hh1, W_fc, b_fc, out);
}